// Round 1
// baseline (41.394 us; speedup 1.0000x reference)
//
#include <hip/hip_runtime.h>
#include <hip/hip_bf16.h>
#include <math.h>

// Problem dims (fixed by reference setup_inputs)
#define B 8
#define NPTS 20000
#define M 1024
#define H 1024
#define BN_EPS 1e-5f

#define BPS_BLOCK 256
#define BPS_CHUNK 250           // 80 chunks * 250 = 20000 exactly
#define BPS_NCHUNK 80
#define L1_MCHUNK 128           // 8 m-chunks of 128

// ---------------------------------------------------------------------------
// Kernel A: init fmin (uint bits of +inf) and h (b1 bias) in workspace
// ---------------------------------------------------------------------------
__global__ __launch_bounds__(256) void init_kernel(unsigned int* __restrict__ fmin,
                                                   float* __restrict__ h,
                                                   const float* __restrict__ b1) {
    int idx = blockIdx.x * 256 + threadIdx.x;          // 0..16383
    if (idx < B * M) {
        fmin[idx] = 0x7F800000u;                       // +inf
    } else {
        int j = idx - B * M;                           // 0..8191 -> h[b][i]
        h[j] = b1[j & (H - 1)];
    }
}

// ---------------------------------------------------------------------------
// Kernel B: BPS partial min over one N-chunk.
// grid = (80 chunks, 8 batches), block = 256 threads, 4 basis pts / thread.
// dist2 = (x2n + b2m) - 2*dot(p, b)  via 3 fma with pre-negated-doubled basis.
// min over n in registers (signed-correct fminf), clamp >=0, then uint atomicMin.
// ---------------------------------------------------------------------------
__global__ __launch_bounds__(256) void bps_kernel(const float* __restrict__ x,
                                                  const float* __restrict__ basis,
                                                  unsigned int* __restrict__ fmin) {
    __shared__ float4 pts[BPS_CHUNK];
    const int chunk = blockIdx.x;
    const int b = blockIdx.y;
    const int tid = threadIdx.x;
    const int n0 = chunk * BPS_CHUNK;
    const float* xb = x + (size_t)b * 3 * NPTS;

    for (int i = tid; i < BPS_CHUNK; i += BPS_BLOCK) {
        float px = xb[n0 + i];
        float py = xb[NPTS + n0 + i];
        float pz = xb[2 * NPTS + n0 + i];
        pts[i] = make_float4(px, py, pz, px * px + py * py + pz * pz);
    }

    float nbx[4], nby[4], nbz[4], bb2[4];
#pragma unroll
    for (int k = 0; k < 4; ++k) {
        int m = tid + k * 256;
        float bx = basis[m * 3 + 0];
        float by = basis[m * 3 + 1];
        float bz = basis[m * 3 + 2];
        nbx[k] = -2.0f * bx;
        nby[k] = -2.0f * by;
        nbz[k] = -2.0f * bz;
        bb2[k] = bx * bx + by * by + bz * bz;
    }
    float acc[4] = {INFINITY, INFINITY, INFINITY, INFINITY};
    __syncthreads();

#pragma unroll 2
    for (int n = 0; n < BPS_CHUNK; n += 2) {
        float4 p0 = pts[n];
        float4 p1 = pts[n + 1];
#pragma unroll
        for (int k = 0; k < 4; ++k) {
            float s0 = p0.w + bb2[k];
            s0 = fmaf(p0.x, nbx[k], s0);
            s0 = fmaf(p0.y, nby[k], s0);
            s0 = fmaf(p0.z, nbz[k], s0);
            float s1 = p1.w + bb2[k];
            s1 = fmaf(p1.x, nbx[k], s1);
            s1 = fmaf(p1.y, nby[k], s1);
            s1 = fmaf(p1.z, nbz[k], s1);
            acc[k] = fminf(acc[k], fminf(s0, s1));
        }
    }

#pragma unroll
    for (int k = 0; k < 4; ++k) {
        float v = fmaxf(acc[k], 0.0f);                 // clip(min,0) == min(clip)
        atomicMin(&fmin[b * M + tid + k * 256], __float_as_uint(v));
    }
}

// ---------------------------------------------------------------------------
// Kernel C: layer1 partial GEMV. grid = (4 i-tiles, 8 m-chunks), block 256.
// Stages bn1(sqrt(fmin)) for its m-chunk (all 8 batches) into LDS, then each
// thread owns one output i and accumulates 8 batch dots over the chunk.
// ---------------------------------------------------------------------------
__global__ __launch_bounds__(256) void layer1_kernel(const unsigned int* __restrict__ fmin,
                                                     const float* __restrict__ g1,
                                                     const float* __restrict__ bb1,
                                                     const float* __restrict__ rm1,
                                                     const float* __restrict__ rv1,
                                                     const float* __restrict__ w1,
                                                     float* __restrict__ h) {
    __shared__ float fs[B][L1_MCHUNK];
    const int tid = threadIdx.x;
    const int i = blockIdx.x * 256 + tid;
    const int m0 = blockIdx.y * L1_MCHUNK;

    for (int e = tid; e < B * L1_MCHUNK; e += 256) {
        int bb = e >> 7;                                // /128
        int ml = e & (L1_MCHUNK - 1);
        int m = m0 + ml;
        float f = sqrtf(__uint_as_float(fmin[bb * M + m]));
        float sc = g1[m] / sqrtf(rv1[m] + BN_EPS);
        fs[bb][ml] = (f - rm1[m]) * sc + bb1[m];
    }
    __syncthreads();

    float acc[B] = {0, 0, 0, 0, 0, 0, 0, 0};
    const float* wrow = w1 + (size_t)i * M + m0;
    for (int ml = 0; ml < L1_MCHUNK; ml += 4) {
        float4 w = *reinterpret_cast<const float4*>(wrow + ml);
#pragma unroll
        for (int bb = 0; bb < B; ++bb) {
            float4 f = *reinterpret_cast<const float4*>(&fs[bb][ml]);
            acc[bb] = fmaf(f.x, w.x, acc[bb]);
            acc[bb] = fmaf(f.y, w.y, acc[bb]);
            acc[bb] = fmaf(f.z, w.z, acc[bb]);
            acc[bb] = fmaf(f.w, w.w, acc[bb]);
        }
    }
#pragma unroll
    for (int bb = 0; bb < B; ++bb) atomicAdd(&h[bb * H + i], acc[bb]);
}

// ---------------------------------------------------------------------------
// Kernel D: relu + bn2 + dot with w2 + b2. grid = 8 (one block per batch).
// ---------------------------------------------------------------------------
__global__ __launch_bounds__(256) void final_kernel(const float* __restrict__ h,
                                                    const float* __restrict__ g2,
                                                    const float* __restrict__ bb2v,
                                                    const float* __restrict__ rm2,
                                                    const float* __restrict__ rv2,
                                                    const float* __restrict__ w2,
                                                    const float* __restrict__ b2,
                                                    float* __restrict__ out) {
    const int b = blockIdx.x;
    const int tid = threadIdx.x;
    float sum = 0.0f;
    for (int i = tid; i < H; i += 256) {
        float v = fmaxf(h[b * H + i], 0.0f);
        float sc = g2[i] / sqrtf(rv2[i] + BN_EPS);
        v = (v - rm2[i]) * sc + bb2v[i];
        sum += v * w2[i];
    }
#pragma unroll
    for (int off = 32; off > 0; off >>= 1) sum += __shfl_down(sum, off, 64);
    __shared__ float wsum[4];
    if ((tid & 63) == 0) wsum[tid >> 6] = sum;
    __syncthreads();
    if (tid == 0) out[b] = wsum[0] + wsum[1] + wsum[2] + wsum[3] + b2[0];
}

// ---------------------------------------------------------------------------
extern "C" void kernel_launch(void* const* d_in, const int* in_sizes, int n_in,
                              void* d_out, int out_size, void* d_ws, size_t ws_size,
                              hipStream_t stream) {
    const float* x      = (const float*)d_in[0];
    const float* basis  = (const float*)d_in[1];
    const float* bn1_g  = (const float*)d_in[2];
    const float* bn1_b  = (const float*)d_in[3];
    const float* bn1_rm = (const float*)d_in[4];
    const float* bn1_rv = (const float*)d_in[5];
    const float* w1     = (const float*)d_in[6];
    const float* b1     = (const float*)d_in[7];
    const float* bn2_g  = (const float*)d_in[8];
    const float* bn2_b  = (const float*)d_in[9];
    const float* bn2_rm = (const float*)d_in[10];
    const float* bn2_rv = (const float*)d_in[11];
    const float* w2     = (const float*)d_in[12];
    const float* b2     = (const float*)d_in[13];
    float* out = (float*)d_out;

    unsigned int* fmin = (unsigned int*)d_ws;                      // 8192 * 4B
    float* h = (float*)((char*)d_ws + (size_t)B * M * 4);          // 8192 * 4B

    init_kernel<<<(2 * B * M) / 256, 256, 0, stream>>>(fmin, h, b1);

    dim3 gB(BPS_NCHUNK, B);
    bps_kernel<<<gB, BPS_BLOCK, 0, stream>>>(x, basis, fmin);

    dim3 gC(H / 256, M / L1_MCHUNK);
    layer1_kernel<<<gC, 256, 0, stream>>>(fmin, bn1_g, bn1_b, bn1_rm, bn1_rv, w1, h);

    final_kernel<<<B, 256, 0, stream>>>(h, bn2_g, bn2_b, bn2_rm, bn2_rv, w2, b2, out);
}